// Round 13
// baseline (46.365 us; speedup 1.0000x reference)
//
#include <hip/hip_runtime.h>
#include <math.h>

#define Bq 2
#define Tq 96
#define Nq 64
#define CIN 16
#define COUT 32
#define PATCH 24
#define NPq 4
#define ATT_SIZE (Bq * Nq * Nq * Tq * COUT)   // 25165824
#define H_ROWS (Bq * NPq * Nq * PATCH)        // 12288
#define SLAB (Nq * PATCH * COUT)              // 49152 floats per (b,s)
#define INV_SIZE (Bq * Nq * Nq * Tq)          // 786432 floats = 3 MB

typedef float f4 __attribute__((ext_vector_type(4)));

// ---------------------------------------------------------------------------
// Kernel 1: h = x_flat(12288,16) @ W(16,32).
// ---------------------------------------------------------------------------
__global__ __launch_bounds__(256) void h_gemm_kernel(
    const float* __restrict__ x, const float* __restrict__ W,
    float* __restrict__ h) {
    __shared__ float Wl[CIN * COUT];
    __shared__ float xs[8 * CIN];
    int tid = threadIdx.x;
    Wl[tid]       = W[tid];
    Wl[tid + 256] = W[tid + 256];
    if (tid < 8 * CIN) xs[tid] = x[blockIdx.x * (8 * CIN) + tid];
    __syncthreads();
    int rl = tid >> 5;
    int c  = tid & 31;
    float acc = 0.f;
#pragma unroll
    for (int k = 0; k < CIN; ++k)
        acc += xs[rl * CIN + k] * Wl[k * COUT + c];
    h[blockIdx.x * 256 + tid] = acc;
}

// ---------------------------------------------------------------------------
// Kernel A: r6 structure, but stores only the softmax reciprocal denominators
// inv[b,i,j,t] (3 MB) + the fused h_prime epilogue. All the exp/shfl/chain
// work with ~3% of the writes.
// ---------------------------------------------------------------------------
__global__ __launch_bounds__(768) void denom_kernel(
    const float* __restrict__ h, const float* __restrict__ adj,
    float* __restrict__ inv, float* __restrict__ hprime) {
    const int bi = blockIdx.x;
    const int s  = bi & 3;
    const int i  = (bi >> 2) & 63;
    const int b  = bi >> 8;
    const int tid  = threadIdx.x;
    const int c4   = tid & 7;
    const int c0   = c4 * 4;
    const int p    = (tid >> 3) % PATCH;
    const int jsub = tid / 192;
    const int j0   = jsub * 16;

    __shared__ float adjrow[Nq];
    __shared__ f4 red[768];
    if (tid < Nq) adjrow[tid] = adj[i * Nq + tid];
    __syncthreads();

    const float* hb = h + (size_t)(b * NPq + s) * SLAB;
    const f4 hi = *(const f4*)(hb + (i * PATCH + p) * COUT + c0);

    f4 acc = {0.f, 0.f, 0.f, 0.f};
    const int t = p * NPq + s;
    // inv flat: ((b*N+i)*N + j)*T + t
    const size_t invbase = ((size_t)((b * Nq + i) * Nq + j0)) * Tq + t;

#pragma unroll
    for (int jj = 0; jj < 16; ++jj) {
        const f4 hj = *(const f4*)(hb + ((j0 + jj) * PATCH + p) * COUT + c0);
        const float aj = adjrow[j0 + jj];

        f4 e = hi * hj;
        e.x = fmaxf(e.x, 0.2f * e.x) * aj;
        e.y = fmaxf(e.y, 0.2f * e.y) * aj;
        e.z = fmaxf(e.z, 0.2f * e.z) * aj;
        e.w = fmaxf(e.w, 0.2f * e.w) * aj;

        f4 ex;
        ex.x = __expf(e.x); ex.y = __expf(e.y);
        ex.z = __expf(e.z); ex.w = __expf(e.w);
        float sm = (ex.x + ex.y) + (ex.z + ex.w);
#pragma unroll
        for (int d = 1; d < 8; d <<= 1) sm += __shfl_xor(sm, d);
        const float iv = __builtin_amdgcn_rcpf(sm);
        acc += ex * iv;
        if (c4 == 0) inv[invbase + (size_t)jj * Tq] = iv;
    }

    red[tid] = acc;
    __syncthreads();

    if (jsub == 0) {
        const f4 a0 = red[tid];
        const f4 a1 = red[tid + 192];
        const f4 a2 = red[tid + 384];
        const f4 a3 = red[tid + 576];
        f4 asum = (a0 + a1) + (a2 + a3);

        const int s2 = t / PATCH;
        const int p2 = t % PATCH;
        const f4 hv = *(const f4*)(h + (size_t)((b * NPq + s2) * Nq + i) * (PATCH * COUT)
                                     + p2 * COUT + c0);
        f4 v = asum * hv;
        v.x = v.x >= 0.f ? v.x : expm1f(v.x);
        v.y = v.y >= 0.f ? v.y : expm1f(v.y);
        v.z = v.z >= 0.f ? v.z : expm1f(v.z);
        v.w = v.w >= 0.f ? v.w : expm1f(v.w);
        *(f4*)(hprime + ((size_t)((b * Nq + i) * Tq + t)) * COUT + c0) = v;
    }
}

// ---------------------------------------------------------------------------
// Kernel B: pure attention stream. Recomputes e (bit-identical ops), loads
// inv, stores exp(e)*inv. Zero LDS, zero barrier, zero shfl, no reduction —
// maximal ILP streaming write. Block = (b, i, jc): 1024 blocks x 768 threads,
// 8 j's per block.
// ---------------------------------------------------------------------------
__global__ __launch_bounds__(768) void attwrite_kernel(
    const float* __restrict__ h, const float* __restrict__ adj,
    const float* __restrict__ inv, float* __restrict__ att) {
    const int g  = blockIdx.x;
    const int jc = g & 7;
    const int i  = (g >> 3) & 63;
    const int b  = g >> 9;
    const int j0 = jc * 8;
    const int tid = threadIdx.x;
    const int c0 = (tid & 7) * 4;
    const int t  = tid >> 3;        // 0..95
    const int s  = t & 3;
    const int p  = t >> 2;

    const float* hb = h + (size_t)(b * NPq + s) * SLAB;
    const f4 hi = *(const f4*)(hb + (i * PATCH + p) * COUT + c0);

    // att flat: (((b*N+i)*N+j)*T + t)*COUT + c
    const size_t outbase = ((size_t)((b * Nq + i) * Nq + j0) * Tq + t) * COUT + c0;
    const size_t jstride = (size_t)Tq * COUT;   // 3072
    const size_t invbase = ((size_t)((b * Nq + i) * Nq + j0)) * Tq + t;

#pragma unroll
    for (int jj = 0; jj < 8; ++jj) {
        const float aj = adj[i * Nq + j0 + jj];
        const f4 hj = *(const f4*)(hb + ((j0 + jj) * PATCH + p) * COUT + c0);

        f4 e = hi * hj;
        e.x = fmaxf(e.x, 0.2f * e.x) * aj;
        e.y = fmaxf(e.y, 0.2f * e.y) * aj;
        e.z = fmaxf(e.z, 0.2f * e.z) * aj;
        e.w = fmaxf(e.w, 0.2f * e.w) * aj;

        f4 ex;
        ex.x = __expf(e.x); ex.y = __expf(e.y);
        ex.z = __expf(e.z); ex.w = __expf(e.w);

        const float iv = inv[invbase + (size_t)jj * Tq];
        *(f4*)(att + outbase + (size_t)jj * jstride) = ex * iv;
    }
}

extern "C" void kernel_launch(void* const* d_in, const int* in_sizes, int n_in,
                              void* d_out, int out_size, void* d_ws, size_t ws_size,
                              hipStream_t stream) {
    (void)in_sizes; (void)n_in; (void)out_size; (void)ws_size;
    const float* x   = (const float*)d_in[0];
    const float* adj = (const float*)d_in[1];
    const float* W   = (const float*)d_in[2];

    float* h   = (float*)d_ws;                    // 393216 floats
    float* inv = (float*)d_ws + H_ROWS * COUT;    // 786432 floats (3 MB)
    float* att = (float*)d_out;
    float* hp  = (float*)d_out + ATT_SIZE;

    hipLaunchKernelGGL(h_gemm_kernel, dim3(H_ROWS / 8), dim3(256), 0, stream,
                       x, W, h);
    // (b, i, s) = 512 blocks: denominators + h_prime
    hipLaunchKernelGGL(denom_kernel, dim3(Bq * Nq * NPq), dim3(768), 0, stream,
                       h, adj, inv, hp);
    // (b, i, jc) = 2*64*8 = 1024 blocks: pure att stream
    hipLaunchKernelGGL(attwrite_kernel, dim3(Bq * Nq * 8), dim3(768), 0, stream,
                       h, adj, inv, att);
}

// Round 14
// 28.813 us; speedup vs baseline: 1.6092x; 1.6092x over previous
//
#include <hip/hip_runtime.h>
#include <math.h>

#define Bq 2
#define Tq 96
#define Nq 64
#define CIN 16
#define COUT 32
#define PATCH 24
#define NPq 4
#define ATT_SIZE (Bq * Nq * Nq * Tq * COUT)   // 25165824
#define H_ROWS (Bq * NPq * Nq * PATCH)        // 12288

typedef float f4 __attribute__((ext_vector_type(4)));

// ---------------------------------------------------------------------------
// Kernel 1: h = x_flat(12288,16) @ W(16,32).  Row-major reshape makes the
// patched view a flat GEMM: h row r = b*6144 + s*1536 + node*24 + p.
// ---------------------------------------------------------------------------
__global__ __launch_bounds__(256) void h_gemm_kernel(
    const float* __restrict__ x, const float* __restrict__ W,
    float* __restrict__ h) {
    __shared__ float Wl[CIN * COUT];
    __shared__ float xs[8 * CIN];
    int tid = threadIdx.x;
    Wl[tid]       = W[tid];
    Wl[tid + 256] = W[tid + 256];
    if (tid < 8 * CIN) xs[tid] = x[blockIdx.x * (8 * CIN) + tid];
    __syncthreads();
    int rl = tid >> 5;
    int c  = tid & 31;
    float acc = 0.f;
#pragma unroll
    for (int k = 0; k < CIN; ++k)
        acc += xs[rl * CIN + k] * Wl[k * COUT + c];
    h[blockIdx.x * 256 + tid] = acc;
}

// ---------------------------------------------------------------------------
// Kernel 2 (fused): one block per (b, i, s). 768 threads = 4 j-subsets x
// 24 p x 8 c-lanes (float4 channels). Each j-subset covers 16 j's; the
// 4 partial sum-over-j vectors meet in LDS, then the block finalizes
// h_prime = elu(sum * h_flat) itself. Round-6 champion configuration:
// plain stores (NT hurt), in-loop loads (hoisting neutral), default
// block order (XCD swizzle neutral), 24 waves/CU (occupancy insensitive).
// ---------------------------------------------------------------------------
__global__ __launch_bounds__(768) void att_fused_kernel(
    const float* __restrict__ h, const float* __restrict__ adj,
    float* __restrict__ att, float* __restrict__ hprime) {
    const int bi = blockIdx.x;
    const int s  = bi & 3;
    const int i  = (bi >> 2) & 63;
    const int b  = bi >> 8;
    const int tid  = threadIdx.x;
    const int c0   = (tid & 7) * 4;      // channel quad base
    const int p    = (tid >> 3) % PATCH; // 0..23
    const int jsub = tid / 192;          // 0..3
    const int j0   = jsub * 16;

    __shared__ float adjrow[Nq];
    __shared__ f4 red[768];
    if (tid < Nq) adjrow[tid] = adj[i * Nq + tid];
    __syncthreads();

    const float* hb = h + (size_t)((b * NPq + s) * Nq) * (PATCH * COUT);
    const f4 hi = *(const f4*)(hb + (i * PATCH + p) * COUT + c0);

    f4 acc = {0.f, 0.f, 0.f, 0.f};
    const int t = p * NPq + s;
    // att flat index: (((b*N+i)*N+j)*T + t)*COUT + c
    size_t outbase = ((size_t)((b * Nq + i) * Nq + j0) * Tq + t) * COUT + c0;
    const size_t jstride = (size_t)Tq * COUT;   // 3072

#pragma unroll 4
    for (int jj = 0; jj < 16; ++jj) {
        const f4 hj = *(const f4*)(hb + ((j0 + jj) * PATCH + p) * COUT + c0);
        const float aj = adjrow[j0 + jj];

        f4 e = hi * hj;
        e.x = fmaxf(e.x, 0.2f * e.x) * aj;   // LeakyReLU(0.2) then *adj
        e.y = fmaxf(e.y, 0.2f * e.y) * aj;
        e.z = fmaxf(e.z, 0.2f * e.z) * aj;
        e.w = fmaxf(e.w, 0.2f * e.w) * aj;

        f4 ex;
        ex.x = __expf(e.x); ex.y = __expf(e.y);
        ex.z = __expf(e.z); ex.w = __expf(e.w);
        float sm = (ex.x + ex.y) + (ex.z + ex.w);
#pragma unroll
        for (int d = 1; d < 8; d <<= 1) sm += __shfl_xor(sm, d);
        const float inv = __builtin_amdgcn_rcpf(sm);
        f4 a = ex * inv;
        acc += a;
        *(f4*)(att + outbase + (size_t)jj * jstride) = a;
    }

    red[tid] = acc;
    __syncthreads();

    if (jsub == 0) {
        const f4 a0 = red[tid];
        const f4 a1 = red[tid + 192];
        const f4 a2 = red[tid + 384];
        const f4 a3 = red[tid + 576];
        f4 asum = (a0 + a1) + (a2 + a3);

        // h_flat[b,i,t,c]: t = s2*24 + p2
        const int s2 = t / PATCH;
        const int p2 = t % PATCH;
        const f4 hv = *(const f4*)(h + (size_t)((b * NPq + s2) * Nq + i) * (PATCH * COUT)
                                     + p2 * COUT + c0);
        f4 v = asum * hv;
        v.x = v.x >= 0.f ? v.x : expm1f(v.x);
        v.y = v.y >= 0.f ? v.y : expm1f(v.y);
        v.z = v.z >= 0.f ? v.z : expm1f(v.z);
        v.w = v.w >= 0.f ? v.w : expm1f(v.w);
        *(f4*)(hprime + ((size_t)((b * Nq + i) * Tq + t)) * COUT + c0) = v;
    }
}

extern "C" void kernel_launch(void* const* d_in, const int* in_sizes, int n_in,
                              void* d_out, int out_size, void* d_ws, size_t ws_size,
                              hipStream_t stream) {
    (void)in_sizes; (void)n_in; (void)out_size; (void)ws_size;
    const float* x   = (const float*)d_in[0];
    const float* adj = (const float*)d_in[1];
    const float* W   = (const float*)d_in[2];

    float* h   = (float*)d_ws;              // 393216 floats = 1.57 MB
    float* att = (float*)d_out;
    float* hp  = (float*)d_out + ATT_SIZE;

    hipLaunchKernelGGL(h_gemm_kernel, dim3(H_ROWS / 8), dim3(256), 0, stream,
                       x, W, h);
    // (b, i, s) = 2*64*4 = 512 blocks
    hipLaunchKernelGGL(att_fused_kernel, dim3(Bq * Nq * NPq), dim3(768), 0, stream,
                       h, adj, att, hp);
}